// Round 12
// baseline (441.646 us; speedup 1.0000x reference)
//
#include <hip/hip_runtime.h>
#include <hip/hip_bf16.h>
#include <cstdint>
#include <cstddef>

#define NN 20000
#define KK 32
#define HH 128
#define FFD 512
#define LN_EPS 1e-5f

typedef __attribute__((ext_vector_type(8))) short bf16x8;
typedef __attribute__((ext_vector_type(4))) float f32x4;

__device__ __forceinline__ short f2b(float f){
  __hip_bfloat16 h = __float2bfloat16(f);
  return __builtin_bit_cast(short, h);
}
__device__ __forceinline__ float b2f(short s){
  union { unsigned int u; float f; } v; v.u = ((unsigned int)(unsigned short)s) << 16; return v.f;
}
__device__ __forceinline__ unsigned int pk2(float a, float b){
  return (unsigned int)(unsigned short)f2b(a) | ((unsigned int)(unsigned short)f2b(b) << 16);
}
// tanh-form GELU via hw exp2 + rcp
__device__ __forceinline__ float gelu_fast(float x){
  float u = x * __builtin_fmaf(0.10294278f, x*x, 2.3022082f);
  float e = __builtin_amdgcn_exp2f(u);
  float r = __builtin_amdgcn_rcpf(1.0f + e);
  return __builtin_fmaf(-x, r, x);
}
__device__ __forceinline__ f32x4 MFMA(bf16x8 a, bf16x8 b, f32x4 c){
  return __builtin_amdgcn_mfma_f32_16x16x32_bf16(a, b, c, 0, 0, 0);
}

// ---------------- weight packing ----------------
__global__ __launch_bounds__(256) void enc_pack(
    const float* __restrict__ W1, const float* __restrict__ W2, const float* __restrict__ W3,
    const float* __restrict__ W11, const float* __restrict__ W12, const float* __restrict__ W13,
    const float* __restrict__ Win, const float* __restrict__ Wout,
    short* __restrict__ pk)
{
  const int stride = gridDim.x * blockDim.x;
  for (int idx = blockIdx.x*blockDim.x + threadIdx.x; idx < 294912; idx += stride){
    const float* src = W2; int srow = 0, k, n, NT, NCOLS, base;
    if (idx < 163840){
      int slot = idx >> 14, e = idx & 16383;
      k = e >> 7; n = e & 127; NT = 8; NCOLS = 128; base = slot << 14;
      switch (slot){
        case 0: src = W1;  srow = 0;   break;
        case 1: src = W1;  srow = 256; break;
        case 2: src = W1;  srow = 128; break;
        case 3: src = W2;  srow = 0;   break;
        case 4: src = W3;  srow = 0;   break;
        case 5: src = W11; srow = 0;   break;
        case 6: src = W11; srow = 256; break;
        case 7: src = W11; srow = 128; break;
        case 8: src = W12; srow = 0;   break;
        default: src = W13; srow = 0;  break;
      }
    } else if (idx < 229376){
      int e = idx - 163840; k = e >> 9; n = e & 511; NT = 32; NCOLS = 512; src = Win; base = 163840;
    } else {
      int e = idx - 229376; k = e >> 7; n = e & 127; NT = 8; NCOLS = 128; src = Wout; base = 229376;
    }
    float v = src[(srow + k)*NCOLS + n];
    int out = base + (((k>>5)*NT + (n>>4))*64 + ((k>>3)&3)*16 + (n&15))*8 + (k&7);
    pk[out] = f2b(v);
  }
}

// ---------------- node projections: U = X@Wa + b, Z = X@Wc ----------------
__global__ __launch_bounds__(256, 2) void enc_proj(
    const float* __restrict__ X, const short* __restrict__ pkU, const short* __restrict__ pkZ,
    const float* __restrict__ biasU, short* __restrict__ U, short* __restrict__ Z)
{
  const int lane = threadIdx.x & 63, w = threadIdx.x >> 6;
  const int kgrp = lane >> 4, ccol = lane & 15;
  const int row0 = blockIdx.x*64 + w*16;
  const int arow = row0 + (lane & 15);
  f32x4 accU[8], accZ[8];
  #pragma unroll
  for (int nf=0;nf<8;nf++){ accU[nf] = (f32x4){0,0,0,0}; accZ[nf] = (f32x4){0,0,0,0}; }
  #pragma unroll
  for (int kt=0;kt<4;kt++){
    bf16x8 af = {0,0,0,0,0,0,0,0};
    if (arow < NN){
      const float4* p = (const float4*)(X + (size_t)arow*HH + kt*32 + kgrp*8);
      float4 v0 = p[0], v1 = p[1];
      af[0]=f2b(v0.x); af[1]=f2b(v0.y); af[2]=f2b(v0.z); af[3]=f2b(v0.w);
      af[4]=f2b(v1.x); af[5]=f2b(v1.y); af[6]=f2b(v1.z); af[7]=f2b(v1.w);
    }
    #pragma unroll
    for (int nf=0;nf<8;nf++){
      bf16x8 bu = *(const bf16x8*)(pkU + (((kt<<3)+nf)*64 + lane)*8);
      accU[nf] = MFMA(af, bu, accU[nf]);
      bf16x8 bz = *(const bf16x8*)(pkZ + (((kt<<3)+nf)*64 + lane)*8);
      accZ[nf] = MFMA(af, bz, accZ[nf]);
    }
  }
  #pragma unroll
  for (int nf=0;nf<8;nf++){
    #pragma unroll
    for (int r=0;r<4;r++){
      int grow = row0 + kgrp*4 + r;
      if (grow < NN){
        int col = nf*16 + ccol;
        U[(size_t)grow*HH + col] = f2b(accU[nf][r] + biasU[col]);
        Z[(size_t)grow*HH + col] = f2b(accZ[nf][r]);
      }
    }
  }
}

// ------- fused 3-layer edge MLP: 4 waves, M=32/wave (1 node per wave) -------
// block = 256 threads = 4 waves = 4 nodes = 128 edge rows. Each wave owns ALL 32
// edges of its node -> two A-fragments share every B-fragment read (B LDS traffic
// and issue per row halved vs M=16), and PASS0's masked aggregation is fully
// wave-local (no sPart/barrier). Weights LDS-staged per layer (R8). 2 blocks/CU
// (LDS 68.6KB); __launch_bounds__(256,2) -> 256-VGPR cap, spill impossible at
// ~110 use (R6's failure mode eliminated). EM=1: PASS0 writes bf16 h_E image,
// PASS1 stages/residuals from it (R11).
#define LSTR 136
template<int PASS, int EM>
__global__ __launch_bounds__(256, 2) void enc_mlp3(
    const float* __restrict__ hE,
    const short* __restrict__ Ub, const short* __restrict__ Zb,
    const int*  __restrict__ Eidx,
    const float* __restrict__ maskAtt,
    const float* __restrict__ hV,
    const float* __restrict__ lnG, const float* __restrict__ lnB,
    const short* __restrict__ pkL1,
    const short* __restrict__ pkL2, const float* __restrict__ bias2,
    const short* __restrict__ pkL3, const float* __restrict__ bias3,
    float* __restrict__ outP,
    short* __restrict__ hEs)
{
  __shared__ __align__(16) short sBuf[128*LSTR];  // 34816 B activations
  __shared__ __align__(16) short sW[16384];       // 32768 B current-layer weights
  __shared__ float sB23[256];

  const int i0 = blockIdx.x*4;
  const int t = threadIdx.x;
  const int lane = t & 63, w = t >> 6;          // w in 0..3
  const int kgrp = lane >> 4, ccol = lane & 15;
  const int node = i0 + w;                      // wave's node
  const int rw = w*32;                          // wave's first block-local row
  const size_t ebase = (size_t)i0*KK;           // first edge row of block
  const size_t nbase = (size_t)node*KK;         // first edge row of node

  sB23[t] = (t < 128) ? bias2[t] : bias3[t-128];

  // ---- stage W1 into LDS (8 int4 per thread) ----
  #pragma unroll
  for (int it=0; it<8; it++){
    int idx = it*256 + t;
    *(int4*)(sW + idx*8) = *(const int4*)(pkL1 + idx*8);
  }

  // ---- stage h_E rows rw..rw+31 (wave-local) ----
  if constexpr (EM == 1 && PASS == 1){
    const short* srcS = hEs + nbase*HH;
    #pragma unroll
    for (int it=0; it<8; it++){
      int r16 = it*4 + (lane>>4);
      int c16 = lane & 15;
      int4 v = *(const int4*)(srcS + (size_t)r16*HH + c16*8);
      *(int4*)(sBuf + (rw + r16)*LSTR + c16*8) = v;
    }
  } else {
    const float4* src = (const float4*)(hE + nbase*HH);
    #pragma unroll
    for (int it=0; it<16; it++){
      int r = it*2 + (lane>>5);
      int c4 = lane & 31;
      float4 v = src[r*32 + c4];
      uint2 p; p.x = pk2(v.x, v.y); p.y = pk2(v.z, v.w);
      *(uint2*)(sBuf + (rw + r)*LSTR + c4*4) = p;
      if constexpr (EM == 1 && PASS == 0)
        *(uint2*)(hEs + (nbase + r)*HH + c4*4) = p;
    }
  }
  __syncthreads();   // W1 + sB23 visible

  const short* sRow0 = sBuf + (rw + ccol)*LSTR;
  const short* sRow1 = sBuf + (rw + 16 + ccol)*LSTR;
  f32x4 acc0[8], acc1[8];

  // ---- layer 1 ----
  #pragma unroll
  for (int nf=0;nf<8;nf++){ acc0[nf] = (f32x4){0,0,0,0}; acc1[nf] = (f32x4){0,0,0,0}; }
  #pragma unroll
  for (int kt=0;kt<4;kt++){
    bf16x8 a0 = *(const bf16x8*)(sRow0 + kt*32 + kgrp*8);
    bf16x8 a1 = *(const bf16x8*)(sRow1 + kt*32 + kgrp*8);
    #pragma unroll
    for (int nf=0;nf<8;nf++){
      bf16x8 b = *(const bf16x8*)(sW + (((kt<<3)+nf)*64 + lane)*8);
      acc0[nf] = MFMA(a0, b, acc0[nf]);
      acc1[nf] = MFMA(a1, b, acc1[nf]);
    }
  }
  // Z gather (short liveness); rows wave-private: 2 lanes/row, 8 int4 each
  {
    const int zrow = rw + (lane >> 1);
    const int seg0 = lane & 1;
    const int jj = Eidx[ebase + zrow];
    const int4* zsrc = (const int4*)(Zb + (size_t)jj*HH);
    #pragma unroll
    for (int s=0; s<8; s++){
      int4 z = zsrc[seg0 + 2*s];
      *(int4*)(sBuf + zrow*LSTR + (seg0 + 2*s)*8) = z;
    }
  }
  __syncthreads();   // all waves done reading W1
  // stage W2 (overlaps epilogue-1)
  #pragma unroll
  for (int it=0; it<8; it++){
    int idx = it*256 + t;
    *(int4*)(sW + idx*8) = *(const int4*)(pkL2 + idx*8);
  }
  // epilogue 1: +U +Z, gelu -> msg1 (both row halves)
  #pragma unroll
  for (int nf=0;nf<8;nf++){
    float uv = b2f(Ub[(size_t)node*HH + nf*16 + ccol]);
    #pragma unroll
    for (int r=0;r<4;r++){
      short* p0 = sBuf + (rw + kgrp*4 + r)*LSTR + nf*16 + ccol;
      short* p1 = p0 + 16*LSTR;
      float v0 = acc0[nf][r] + uv + b2f(*p0);
      float v1 = acc1[nf][r] + uv + b2f(*p1);
      *p0 = f2b(gelu_fast(v0));
      *p1 = f2b(gelu_fast(v1));
    }
  }
  __syncthreads();   // W2 visible

  // ---- layer 2 ----
  #pragma unroll
  for (int nf=0;nf<8;nf++){ acc0[nf] = (f32x4){0,0,0,0}; acc1[nf] = (f32x4){0,0,0,0}; }
  #pragma unroll
  for (int kt=0;kt<4;kt++){
    bf16x8 a0 = *(const bf16x8*)(sRow0 + kt*32 + kgrp*8);
    bf16x8 a1 = *(const bf16x8*)(sRow1 + kt*32 + kgrp*8);
    #pragma unroll
    for (int nf=0;nf<8;nf++){
      bf16x8 b = *(const bf16x8*)(sW + (((kt<<3)+nf)*64 + lane)*8);
      acc0[nf] = MFMA(a0, b, acc0[nf]);
      acc1[nf] = MFMA(a1, b, acc1[nf]);
    }
  }
  __syncthreads();   // all waves done reading W2
  // stage W3 (overlaps epilogue-2)
  #pragma unroll
  for (int it=0; it<8; it++){
    int idx = it*256 + t;
    *(int4*)(sW + idx*8) = *(const int4*)(pkL3 + idx*8);
  }
  #pragma unroll
  for (int nf=0;nf<8;nf++){
    float b2v = sB23[nf*16 + ccol];
    #pragma unroll
    for (int r=0;r<4;r++){
      short* p0 = sBuf + (rw + kgrp*4 + r)*LSTR + nf*16 + ccol;
      short* p1 = p0 + 16*LSTR;
      *p0 = f2b(gelu_fast(acc0[nf][r] + b2v));
      *p1 = f2b(gelu_fast(acc1[nf][r] + b2v));
    }
  }
  __syncthreads();   // W3 visible

  // ---- layer 3 ----
  #pragma unroll
  for (int nf=0;nf<8;nf++){ acc0[nf] = (f32x4){0,0,0,0}; acc1[nf] = (f32x4){0,0,0,0}; }
  #pragma unroll
  for (int kt=0;kt<4;kt++){
    bf16x8 a0 = *(const bf16x8*)(sRow0 + kt*32 + kgrp*8);
    bf16x8 a1 = *(const bf16x8*)(sRow1 + kt*32 + kgrp*8);
    #pragma unroll
    for (int nf=0;nf<8;nf++){
      bf16x8 b = *(const bf16x8*)(sW + (((kt<<3)+nf)*64 + lane)*8);
      acc0[nf] = MFMA(a0, b, acc0[nf]);
      acc1[nf] = MFMA(a1, b, acc1[nf]);
    }
  }

  if (PASS == 0){
    // wave owns the whole node: masked colsum over 32 edges, fully in-register
    float m0[4], m1[4];
    {
      float4 a = *(const float4*)(maskAtt + nbase + kgrp*4);
      float4 b = *(const float4*)(maskAtt + nbase + 16 + kgrp*4);
      m0[0]=a.x; m0[1]=a.y; m0[2]=a.z; m0[3]=a.w;
      m1[0]=b.x; m1[1]=b.y; m1[2]=b.z; m1[3]=b.w;
    }
    float x[8];
    #pragma unroll
    for (int nf=0;nf<8;nf++){
      float b3v = sB23[128 + nf*16 + ccol];
      float s = 0.f;
      #pragma unroll
      for (int r=0;r<4;r++){
        s = __builtin_fmaf(acc0[nf][r] + b3v, m0[r], s);
        s = __builtin_fmaf(acc1[nf][r] + b3v, m1[r], s);
      }
      s += __shfl_xor(s, 16);
      s += __shfl_xor(s, 32);
      x[nf] = hV[(size_t)node*HH + nf*16 + ccol] + s*(1.0f/30.0f);
    }
    float sm = 0.f, sq = 0.f;
    #pragma unroll
    for (int nf=0;nf<8;nf++){ sm += x[nf]; sq += x[nf]*x[nf]; }
    #pragma unroll
    for (int off=1; off<16; off<<=1){
      sm += __shfl_xor(sm, off);
      sq += __shfl_xor(sq, off);
    }
    float mean = sm*(1.f/128.f);
    float var  = sq*(1.f/128.f) - mean*mean;
    float inv  = rsqrtf(var + LN_EPS);
    if (kgrp == 0){
      #pragma unroll
      for (int nf=0;nf<8;nf++){
        int col = nf*16 + ccol;
        outP[(size_t)node*HH + col] = (x[nf]-mean)*inv*lnG[col] + lnB[col];
      }
    }
  } else {
    // +b3, +h_E residual, dual in-register LN per row-half
    float rs0[4]={0,0,0,0}, rq0[4]={0,0,0,0}, rs1[4]={0,0,0,0}, rq1[4]={0,0,0,0};
    #pragma unroll
    for (int nf=0;nf<8;nf++){
      float b3v = sB23[128 + nf*16 + ccol];
      #pragma unroll
      for (int r=0;r<4;r++){
        int lrow = kgrp*4 + r, col = nf*16 + ccol;
        float h0, h1;
        if constexpr (EM == 1){
          h0 = b2f(hEs[(nbase + lrow)*HH + col]);
          h1 = b2f(hEs[(nbase + 16 + lrow)*HH + col]);
        } else {
          h0 = hE[(nbase + lrow)*HH + col];
          h1 = hE[(nbase + 16 + lrow)*HH + col];
        }
        float x0 = acc0[nf][r] + b3v + h0;
        float x1 = acc1[nf][r] + b3v + h1;
        acc0[nf][r] = x0; acc1[nf][r] = x1;
        rs0[r] += x0; rq0[r] += x0*x0;
        rs1[r] += x1; rq1[r] += x1*x1;
      }
    }
    #pragma unroll
    for (int off=1; off<16; off<<=1){
      #pragma unroll
      for (int r=0;r<4;r++){
        rs0[r] += __shfl_xor(rs0[r], off);
        rq0[r] += __shfl_xor(rq0[r], off);
        rs1[r] += __shfl_xor(rs1[r], off);
        rq1[r] += __shfl_xor(rq1[r], off);
      }
    }
    #pragma unroll
    for (int r=0;r<4;r++){
      float mean0 = rs0[r]*(1.f/128.f);
      float inv0  = rsqrtf(rq0[r]*(1.f/128.f) - mean0*mean0 + LN_EPS);
      float mean1 = rs1[r]*(1.f/128.f);
      float inv1  = rsqrtf(rq1[r]*(1.f/128.f) - mean1*mean1 + LN_EPS);
      #pragma unroll
      for (int nf=0;nf<8;nf++){
        int lrow = kgrp*4 + r, col = nf*16 + ccol;
        __builtin_nontemporal_store((acc0[nf][r]-mean0)*inv0*lnG[col] + lnB[col],
                                    &outP[(nbase + lrow)*HH + col]);
        __builtin_nontemporal_store((acc1[nf][r]-mean1)*inv1*lnG[col] + lnB[col],
                                    &outP[(nbase + 16 + lrow)*HH + col]);
      }
    }
  }
}

// ---------------- fused FFN 128->512->128 + LN2 + mask_V ----------------
__global__ __launch_bounds__(256, 2) void enc_ffn(
    const float* __restrict__ X,
    const short* __restrict__ pkWin, const float* __restrict__ bin,
    const short* __restrict__ pkWout, const float* __restrict__ bout,
    const float* __restrict__ g2, const float* __restrict__ b2ln,
    const float* __restrict__ maskV,
    float* __restrict__ out)
{
  __shared__ short sT[64*512];
  const int t = threadIdx.x, lane = t & 63, w = t >> 6;
  const int kgrp = lane >> 4, ccol = lane & 15;
  const int row0 = blockIdx.x*64;
  const int arow = row0 + w*16 + (lane & 15);
  f32x4 acc[32];
  #pragma unroll
  for (int nf=0;nf<32;nf++) acc[nf] = (f32x4){0,0,0,0};
  #pragma unroll
  for (int kt=0;kt<4;kt++){
    bf16x8 af = {0,0,0,0,0,0,0,0};
    if (arow < NN){
      const float4* p = (const float4*)(X + (size_t)arow*HH + kt*32 + kgrp*8);
      float4 v0 = p[0], v1 = p[1];
      af[0]=f2b(v0.x); af[1]=f2b(v0.y); af[2]=f2b(v0.z); af[3]=f2b(v0.w);
      af[4]=f2b(v1.x); af[5]=f2b(v1.y); af[6]=f2b(v1.z); af[7]=f2b(v1.w);
    }
    #pragma unroll
    for (int nf=0;nf<32;nf++){
      bf16x8 b = *(const bf16x8*)(pkWin + ((size_t)((kt<<5)+nf)*64 + lane)*8);
      acc[nf] = MFMA(af, b, acc[nf]);
    }
  }
  #pragma unroll
  for (int nf=0;nf<32;nf++){
    #pragma unroll
    for (int r=0;r<4;r++){
      int rl = w*16 + kgrp*4 + r, col = nf*16 + ccol;
      sT[rl*512 + (col ^ ((rl&7)<<3))] = f2b(gelu_fast(acc[nf][r] + bin[col]));
    }
  }
  f32x4 a2[8];
  #pragma unroll
  for (int nf=0;nf<8;nf++) a2[nf] = (f32x4){0,0,0,0};
  const int rl_a = w*16 + (lane & 15);
  #pragma unroll
  for (int kt=0;kt<16;kt++){
    int base = kt*32 + kgrp*8;
    bf16x8 af = *(const bf16x8*)(sT + rl_a*512 + (base ^ ((rl_a&7)<<3)));
    #pragma unroll
    for (int nf=0;nf<8;nf++){
      bf16x8 b = *(const bf16x8*)(pkWout + (((kt<<3)+nf)*64 + lane)*8);
      a2[nf] = MFMA(af, b, a2[nf]);
    }
  }
  float rsum[4] = {0,0,0,0}, rsq[4] = {0,0,0,0};
  #pragma unroll
  for (int nf=0;nf<8;nf++){
    #pragma unroll
    for (int r=0;r<4;r++){
      int grow = row0 + w*16 + kgrp*4 + r, col = nf*16 + ccol;
      float prev = (grow < NN) ? X[(size_t)grow*HH + col] : 0.f;
      float x = a2[nf][r] + bout[col] + prev;
      a2[nf][r] = x;
      rsum[r] += x; rsq[r] += x*x;
    }
  }
  #pragma unroll
  for (int off=1; off<16; off<<=1){
    #pragma unroll
    for (int r=0;r<4;r++){
      rsum[r] += __shfl_xor(rsum[r], off);
      rsq[r]  += __shfl_xor(rsq[r], off);
    }
  }
  #pragma unroll
  for (int r=0;r<4;r++){
    int grow = row0 + w*16 + kgrp*4 + r;
    float mean = rsum[r]*(1.f/128.f);
    float var  = rsq[r]*(1.f/128.f) - mean*mean;
    float inv  = rsqrtf(var + LN_EPS);
    float mv   = (grow < NN) ? maskV[grow] : 0.f;
    #pragma unroll
    for (int nf=0;nf<8;nf++){
      int col = nf*16 + ccol;
      if (grow < NN)
        out[(size_t)grow*HH + col] = mv * ((a2[nf][r]-mean)*inv*g2[col] + b2ln[col]);
    }
  }
}

// ---------------- host ----------------
extern "C" void kernel_launch(void* const* d_in, const int* in_sizes, int n_in,
                              void* d_out, int out_size, void* d_ws, size_t ws_size,
                              hipStream_t stream)
{
  const float* h_V   = (const float*)d_in[0];
  const float* h_E   = (const float*)d_in[1];
  const float* maskV = (const float*)d_in[2];
  const float* maskA = (const float*)d_in[3];
  const float* W1w  = (const float*)d_in[4];  const float* W1b  = (const float*)d_in[5];
  const float* W2w  = (const float*)d_in[6];  const float* W2b  = (const float*)d_in[7];
  const float* W3w  = (const float*)d_in[8];  const float* W3b  = (const float*)d_in[9];
  const float* W11w = (const float*)d_in[10]; const float* W11b = (const float*)d_in[11];
  const float* W12w = (const float*)d_in[12]; const float* W12b = (const float*)d_in[13];
  const float* W13w = (const float*)d_in[14]; const float* W13b = (const float*)d_in[15];
  const float* Winw = (const float*)d_in[16]; const float* Winb = (const float*)d_in[17];
  const float* Woutw= (const float*)d_in[18]; const float* Woutb= (const float*)d_in[19];
  const float* ln1g = (const float*)d_in[20]; const float* ln1b = (const float*)d_in[21];
  const float* ln2g = (const float*)d_in[22]; const float* ln2b = (const float*)d_in[23];
  const float* ln3g = (const float*)d_in[24]; const float* ln3b = (const float*)d_in[25];
  const int*   Eidx = (const int*)d_in[26];

  float* outV = (float*)d_out;
  float* outE = outV + (size_t)NN*HH;

  char* ws = (char*)d_ws;
  short* pk = (short*)ws;
  const short* pkW1a  = pk + 0*16384;
  const short* pkW1c  = pk + 1*16384;
  const short* pkW1bb = pk + 2*16384;
  const short* pkW2   = pk + 3*16384;
  const short* pkW3   = pk + 4*16384;
  const short* pkW11a = pk + 5*16384;
  const short* pkW11c = pk + 6*16384;
  const short* pkW11bb= pk + 7*16384;
  const short* pkW12  = pk + 8*16384;
  const short* pkW13  = pk + 9*16384;
  const short* pkWin  = pk + 163840;
  const short* pkWout = pk + 229376;

  short* U1 = (short*)(ws + 1048576);
  short* Z1 = (short*)(ws + 6291456);
  short* U2 = (short*)(ws + 11534336);
  short* Z2 = (short*)(ws + 16777216);
  float* hVmid = (float*)(ws + 22020096);
  short* hEs = (short*)(ws + 33554432);   // bf16 image of h_E, 163.84 MB

  const bool em = ws_size >= (size_t)33554432 + (size_t)NN*KK*HH*2;

  enc_pack<<<288, 256, 0, stream>>>(W1w, W2w, W3w, W11w, W12w, W13w, Winw, Woutw, pk);
  enc_proj<<<313, 256, 0, stream>>>(h_V, pkW1a, pkW1c, W1b, U1, Z1);
  if (em){
    enc_mlp3<0,1><<<NN/4, 256, 0, stream>>>(h_E, U1, Z1, Eidx, maskA, h_V,
                                            ln1g, ln1b, pkW1bb, pkW2, W2b, pkW3, W3b, hVmid, hEs);
  } else {
    enc_mlp3<0,0><<<NN/4, 256, 0, stream>>>(h_E, U1, Z1, Eidx, maskA, h_V,
                                            ln1g, ln1b, pkW1bb, pkW2, W2b, pkW3, W3b, hVmid, nullptr);
  }
  enc_ffn<<<313, 256, 0, stream>>>(hVmid, pkWin, Winb, pkWout, Woutb,
                                   ln2g, ln2b, maskV, outV);
  enc_proj<<<313, 256, 0, stream>>>(outV, pkW11a, pkW11c, W11b, U2, Z2);
  if (em){
    enc_mlp3<1,1><<<NN/4, 256, 0, stream>>>(h_E, U2, Z2, Eidx, nullptr, nullptr,
                                            ln3g, ln3b, pkW11bb, pkW12, W12b, pkW13, W13b, outE, hEs);
  } else {
    enc_mlp3<1,0><<<NN/4, 256, 0, stream>>>(h_E, U2, Z2, Eidx, nullptr, nullptr,
                                            ln3g, ln3b, pkW11bb, pkW12, W12b, pkW13, W13b, outE, nullptr);
  }
}

// Round 14
// 411.035 us; speedup vs baseline: 1.0745x; 1.0745x over previous
//
#include <hip/hip_runtime.h>
#include <hip/hip_bf16.h>
#include <cstdint>
#include <cstddef>

#define NN 20000
#define KK 32
#define HH 128
#define FFD 512
#define LN_EPS 1e-5f

typedef __attribute__((ext_vector_type(8))) short bf16x8;
typedef __attribute__((ext_vector_type(4))) float f32x4;

__device__ __forceinline__ short f2b(float f){
  __hip_bfloat16 h = __float2bfloat16(f);
  return __builtin_bit_cast(short, h);
}
__device__ __forceinline__ float b2f(short s){
  union { unsigned int u; float f; } v; v.u = ((unsigned int)(unsigned short)s) << 16; return v.f;
}
__device__ __forceinline__ unsigned int pk2(float a, float b){
  return (unsigned int)(unsigned short)f2b(a) | ((unsigned int)(unsigned short)f2b(b) << 16);
}
// tanh-form GELU via hw exp2 + rcp
__device__ __forceinline__ float gelu_fast(float x){
  float u = x * __builtin_fmaf(0.10294278f, x*x, 2.3022082f);
  float e = __builtin_amdgcn_exp2f(u);
  float r = __builtin_amdgcn_rcpf(1.0f + e);
  return __builtin_fmaf(-x, r, x);
}
__device__ __forceinline__ f32x4 MFMA(bf16x8 a, bf16x8 b, f32x4 c){
  return __builtin_amdgcn_mfma_f32_16x16x32_bf16(a, b, c, 0, 0, 0);
}
// async global->LDS, 16B per lane; dest = wave-uniform base + lane*16
__device__ __forceinline__ void gload_lds16(const short* g, short* l){
  __builtin_amdgcn_global_load_lds(
      (const __attribute__((address_space(1))) void*)g,
      (__attribute__((address_space(3))) void*)l,
      16, 0, 0);
}

// ---------------- weight packing ----------------
__global__ __launch_bounds__(256) void enc_pack(
    const float* __restrict__ W1, const float* __restrict__ W2, const float* __restrict__ W3,
    const float* __restrict__ W11, const float* __restrict__ W12, const float* __restrict__ W13,
    const float* __restrict__ Win, const float* __restrict__ Wout,
    short* __restrict__ pk)
{
  const int stride = gridDim.x * blockDim.x;
  for (int idx = blockIdx.x*blockDim.x + threadIdx.x; idx < 294912; idx += stride){
    const float* src = W2; int srow = 0, k, n, NT, NCOLS, base;
    if (idx < 163840){
      int slot = idx >> 14, e = idx & 16383;
      k = e >> 7; n = e & 127; NT = 8; NCOLS = 128; base = slot << 14;
      switch (slot){
        case 0: src = W1;  srow = 0;   break;
        case 1: src = W1;  srow = 256; break;
        case 2: src = W1;  srow = 128; break;
        case 3: src = W2;  srow = 0;   break;
        case 4: src = W3;  srow = 0;   break;
        case 5: src = W11; srow = 0;   break;
        case 6: src = W11; srow = 256; break;
        case 7: src = W11; srow = 128; break;
        case 8: src = W12; srow = 0;   break;
        default: src = W13; srow = 0;  break;
      }
    } else if (idx < 229376){
      int e = idx - 163840; k = e >> 9; n = e & 511; NT = 32; NCOLS = 512; src = Win; base = 163840;
    } else {
      int e = idx - 229376; k = e >> 7; n = e & 127; NT = 8; NCOLS = 128; src = Wout; base = 229376;
    }
    float v = src[(srow + k)*NCOLS + n];
    int out = base + (((k>>5)*NT + (n>>4))*64 + ((k>>3)&3)*16 + (n&15))*8 + (k&7);
    pk[out] = f2b(v);
  }
}

// ---------------- node projections: U = X@Wa + b, Z = X@Wc ----------------
__global__ __launch_bounds__(256, 2) void enc_proj(
    const float* __restrict__ X, const short* __restrict__ pkU, const short* __restrict__ pkZ,
    const float* __restrict__ biasU, short* __restrict__ U, short* __restrict__ Z)
{
  const int lane = threadIdx.x & 63, w = threadIdx.x >> 6;
  const int kgrp = lane >> 4, ccol = lane & 15;
  const int row0 = blockIdx.x*64 + w*16;
  const int arow = row0 + (lane & 15);
  f32x4 accU[8], accZ[8];
  #pragma unroll
  for (int nf=0;nf<8;nf++){ accU[nf] = (f32x4){0,0,0,0}; accZ[nf] = (f32x4){0,0,0,0}; }
  #pragma unroll
  for (int kt=0;kt<4;kt++){
    bf16x8 af = {0,0,0,0,0,0,0,0};
    if (arow < NN){
      const float4* p = (const float4*)(X + (size_t)arow*HH + kt*32 + kgrp*8);
      float4 v0 = p[0], v1 = p[1];
      af[0]=f2b(v0.x); af[1]=f2b(v0.y); af[2]=f2b(v0.z); af[3]=f2b(v0.w);
      af[4]=f2b(v1.x); af[5]=f2b(v1.y); af[6]=f2b(v1.z); af[7]=f2b(v1.w);
    }
    #pragma unroll
    for (int nf=0;nf<8;nf++){
      bf16x8 bu = *(const bf16x8*)(pkU + (((kt<<3)+nf)*64 + lane)*8);
      accU[nf] = MFMA(af, bu, accU[nf]);
      bf16x8 bz = *(const bf16x8*)(pkZ + (((kt<<3)+nf)*64 + lane)*8);
      accZ[nf] = MFMA(af, bz, accZ[nf]);
    }
  }
  #pragma unroll
  for (int nf=0;nf<8;nf++){
    #pragma unroll
    for (int r=0;r<4;r++){
      int grow = row0 + kgrp*4 + r;
      if (grow < NN){
        int col = nf*16 + ccol;
        U[(size_t)grow*HH + col] = f2b(accU[nf][r] + biasU[col]);
        Z[(size_t)grow*HH + col] = f2b(accZ[nf][r]);
      }
    }
  }
}

// ---------------- fused 3-layer edge MLP (8 waves, 4 nodes/block) ----------------
// R11 chassis + async weight staging: all three 32KB sW stagings use
// global_load_lds dwordx4 (4 instr/wave, no VGPR round-trip); loads fly during
// the epilogue VALU, drained by the compiler's vmcnt(0) at the next barrier.
// U folded into layer-1 acc init (R8 form). hEs stores non-temporal.
#define LSTR 136
template<int PASS, int EM>
__global__ __launch_bounds__(512, 4) void enc_mlp3(
    const float* __restrict__ hE,
    const short* __restrict__ Ub, const short* __restrict__ Zb,
    const int*  __restrict__ Eidx,
    const float* __restrict__ maskAtt,
    const float* __restrict__ hV,
    const float* __restrict__ lnG, const float* __restrict__ lnB,
    const short* __restrict__ pkL1,
    const short* __restrict__ pkL2, const float* __restrict__ bias2,
    const short* __restrict__ pkL3, const float* __restrict__ bias3,
    float* __restrict__ outP,
    short* __restrict__ hEs)
{
  __shared__ __align__(16) short sBuf[128*LSTR];  // 34816 B activations
  __shared__ __align__(16) short sW[16384];       // 32768 B current-layer weights
  __shared__ float sB23[256];
  __shared__ float sPart[8][128];

  const int i0 = blockIdx.x*4;
  const int t = threadIdx.x;
  const int lane = t & 63, w = t >> 6;          // w in 0..7
  const int kgrp = lane >> 4, ccol = lane & 15;
  const int node = i0 + (w >> 1);
  const int rw = w*16;
  const size_t ebase = (size_t)i0*KK;           // first edge row of block

  if (t < 256) sB23[t] = (t < 128) ? bias2[t] : bias3[t-128];

  // U rows: loaded up-front (short path to acc init; latency hides under staging)
  float ureg[8];
  #pragma unroll
  for (int nf=0; nf<8; nf++) ureg[nf] = b2f(Ub[(size_t)node*HH + nf*16 + ccol]);

  // ---- stage W1 into LDS: async, 4 x 1KB per wave ----
  #pragma unroll
  for (int i=0;i<4;i++)
    gload_lds16(pkL1 + (w*4 + i)*512 + lane*8, sW + (w*4 + i)*512);

  // ---- stage h_E rows rw..rw+15 (wave-local) ----
  if constexpr (EM == 1 && PASS == 1){
    // bf16 source: pure int4 copy
    const short* srcS = hEs + (ebase + rw)*HH;
    #pragma unroll
    for (int it=0; it<4; it++){
      int r16 = it*4 + (lane>>4);
      int c16 = lane & 15;
      int4 v = *(const int4*)(srcS + (size_t)r16*HH + c16*8);
      *(int4*)(sBuf + (rw + r16)*LSTR + c16*8) = v;
    }
  } else {
    // fp32 source -> bf16 (PASS0 always; PASS1 when EM=0)
    const float4* src = (const float4*)(hE + (ebase + rw)*HH);
    #pragma unroll
    for (int it=0; it<8; it++){
      int r = it*2 + (lane>>5);
      int c4 = lane & 31;
      float4 v = src[r*32 + c4];
      unsigned long long p = (unsigned long long)pk2(v.x, v.y)
                           | ((unsigned long long)pk2(v.z, v.w) << 32);
      *(unsigned long long*)(sBuf + (rw + r)*LSTR + c4*4) = p;
      if constexpr (EM == 1 && PASS == 0)
        __builtin_nontemporal_store(p,
            (unsigned long long*)(hEs + (ebase + rw + r)*HH + c4*4));
    }
  }
  __syncthreads();   // W1 (vmcnt-drained) + sB23 visible

  const short* sRow = sBuf + (rw + ccol)*LSTR;
  f32x4 acc[8];

  // ---- layer 1 (acc init = U) ----
  #pragma unroll
  for (int nf=0;nf<8;nf++) acc[nf] = (f32x4){ureg[nf],ureg[nf],ureg[nf],ureg[nf]};
  #pragma unroll
  for (int kt=0;kt<4;kt++){
    bf16x8 af = *(const bf16x8*)(sRow + kt*32 + kgrp*8);
    #pragma unroll
    for (int nf=0;nf<8;nf++){
      bf16x8 b = *(const bf16x8*)(sW + (((kt<<3)+nf)*64 + lane)*8);
      acc[nf] = MFMA(af, b, acc[nf]);
    }
  }
  // Z gather (short liveness); rows wave-private
  {
    const int zrow = rw + (lane >> 2);
    const int seg0 = lane & 3;
    const int jj = Eidx[i0*KK + zrow];
    const int4* zsrc = (const int4*)(Zb + (size_t)jj*HH);
    int4 z0 = zsrc[seg0];
    int4 z1 = zsrc[seg0 + 4];
    int4 z2 = zsrc[seg0 + 8];
    int4 z3 = zsrc[seg0 + 12];
    *(int4*)(sBuf + zrow*LSTR + (seg0     )*8) = z0;
    *(int4*)(sBuf + zrow*LSTR + (seg0 + 4 )*8) = z1;
    *(int4*)(sBuf + zrow*LSTR + (seg0 + 8 )*8) = z2;
    *(int4*)(sBuf + zrow*LSTR + (seg0 + 12)*8) = z3;
  }
  __syncthreads();   // all waves done reading W1
  // stage W2 async (flies during epilogue-1)
  #pragma unroll
  for (int i=0;i<4;i++)
    gload_lds16(pkL2 + (w*4 + i)*512 + lane*8, sW + (w*4 + i)*512);
  // epilogue 1: +Z, gelu -> msg1
  #pragma unroll
  for (int nf=0;nf<8;nf++){
    #pragma unroll
    for (int r=0;r<4;r++){
      short* p = sBuf + (rw + kgrp*4 + r)*LSTR + nf*16 + ccol;
      float v = acc[nf][r] + b2f(*p);
      *p = f2b(gelu_fast(v));
    }
  }
  __syncthreads();   // W2 visible

  // ---- layer 2 ----
  #pragma unroll
  for (int nf=0;nf<8;nf++) acc[nf] = (f32x4){0,0,0,0};
  #pragma unroll
  for (int kt=0;kt<4;kt++){
    bf16x8 af = *(const bf16x8*)(sRow + kt*32 + kgrp*8);
    #pragma unroll
    for (int nf=0;nf<8;nf++){
      bf16x8 b = *(const bf16x8*)(sW + (((kt<<3)+nf)*64 + lane)*8);
      acc[nf] = MFMA(af, b, acc[nf]);
    }
  }
  __syncthreads();   // all waves done reading W2
  // stage W3 async (flies during epilogue-2)
  #pragma unroll
  for (int i=0;i<4;i++)
    gload_lds16(pkL3 + (w*4 + i)*512 + lane*8, sW + (w*4 + i)*512);
  #pragma unroll
  for (int nf=0;nf<8;nf++){
    float b2v = sB23[nf*16 + ccol];
    #pragma unroll
    for (int r=0;r<4;r++){
      short* p = sBuf + (rw + kgrp*4 + r)*LSTR + nf*16 + ccol;
      *p = f2b(gelu_fast(acc[nf][r] + b2v));
    }
  }
  __syncthreads();   // W3 visible

  // ---- layer 3 ----
  #pragma unroll
  for (int nf=0;nf<8;nf++) acc[nf] = (f32x4){0,0,0,0};
  #pragma unroll
  for (int kt=0;kt<4;kt++){
    bf16x8 af = *(const bf16x8*)(sRow + kt*32 + kgrp*8);
    #pragma unroll
    for (int nf=0;nf<8;nf++){
      bf16x8 b = *(const bf16x8*)(sW + (((kt<<3)+nf)*64 + lane)*8);
      acc[nf] = MFMA(af, b, acc[nf]);
    }
  }

  if (PASS == 0){
    float m[4];
    {
      const float4 mv = *(const float4*)(maskAtt + ebase + rw + kgrp*4);
      m[0]=mv.x; m[1]=mv.y; m[2]=mv.z; m[3]=mv.w;
    }
    #pragma unroll
    for (int nf=0;nf<8;nf++){
      float b3v = sB23[128 + nf*16 + ccol];
      float s = 0.f;
      #pragma unroll
      for (int r=0;r<4;r++) s = __builtin_fmaf(acc[nf][r] + b3v, m[r], s);
      s += __shfl_xor(s, 16);
      s += __shfl_xor(s, 32);
      if (kgrp == 0) sPart[w][nf*16 + ccol] = s;
    }
    __syncthreads();
    if ((w & 1) == 0){
      float c0 = sPart[w][lane]    + sPart[w+1][lane];
      float c1 = sPart[w][64+lane] + sPart[w+1][64+lane];
      float x0 = hV[(size_t)node*HH + lane]      + c0*(1.0f/30.0f);
      float x1 = hV[(size_t)node*HH + 64 + lane] + c1*(1.0f/30.0f);
      float sm = x0 + x1, sq = x0*x0 + x1*x1;
      #pragma unroll
      for (int off=1; off<64; off<<=1){
        sm += __shfl_xor(sm, off);
        sq += __shfl_xor(sq, off);
      }
      float mean = sm*(1.f/128.f);
      float var  = sq*(1.f/128.f) - mean*mean;
      float inv  = rsqrtf(var + LN_EPS);
      outP[(size_t)node*HH + lane]      = (x0-mean)*inv*lnG[lane]    + lnB[lane];
      outP[(size_t)node*HH + 64 + lane] = (x1-mean)*inv*lnG[64+lane] + lnB[64+lane];
    }
  } else {
    // +b3, +h_E residual, LN3 in-register per row
    float rs[4] = {0,0,0,0}, rq[4] = {0,0,0,0};
    #pragma unroll
    for (int nf=0;nf<8;nf++){
      float b3v = sB23[128 + nf*16 + ccol];
      #pragma unroll
      for (int r=0;r<4;r++){
        int row = rw + kgrp*4 + r, col = nf*16 + ccol;
        float hres;
        if constexpr (EM == 1) hres = b2f(hEs[(ebase + row)*HH + col]);
        else                   hres = hE[(ebase + row)*HH + col];
        float x = acc[nf][r] + b3v + hres;
        acc[nf][r] = x;
        rs[r] += x; rq[r] += x*x;
      }
    }
    #pragma unroll
    for (int off=1; off<16; off<<=1){
      #pragma unroll
      for (int r=0;r<4;r++){
        rs[r] += __shfl_xor(rs[r], off);
        rq[r] += __shfl_xor(rq[r], off);
      }
    }
    #pragma unroll
    for (int r=0;r<4;r++){
      float mean = rs[r]*(1.f/128.f);
      float var  = rq[r]*(1.f/128.f) - mean*mean;
      float inv  = rsqrtf(var + LN_EPS);
      #pragma unroll
      for (int nf=0;nf<8;nf++){
        int row = rw + kgrp*4 + r, col = nf*16 + ccol;
        __builtin_nontemporal_store((acc[nf][r]-mean)*inv*lnG[col] + lnB[col],
                                    &outP[(ebase + row)*HH + col]);
      }
    }
  }
}

// ---------------- fused FFN 128->512->128 + LN2 + mask_V ----------------
__global__ __launch_bounds__(256, 2) void enc_ffn(
    const float* __restrict__ X,
    const short* __restrict__ pkWin, const float* __restrict__ bin,
    const short* __restrict__ pkWout, const float* __restrict__ bout,
    const float* __restrict__ g2, const float* __restrict__ b2ln,
    const float* __restrict__ maskV,
    float* __restrict__ out)
{
  __shared__ short sT[64*512];
  const int t = threadIdx.x, lane = t & 63, w = t >> 6;
  const int kgrp = lane >> 4, ccol = lane & 15;
  const int row0 = blockIdx.x*64;
  const int arow = row0 + w*16 + (lane & 15);
  f32x4 acc[32];
  #pragma unroll
  for (int nf=0;nf<32;nf++) acc[nf] = (f32x4){0,0,0,0};
  #pragma unroll
  for (int kt=0;kt<4;kt++){
    bf16x8 af = {0,0,0,0,0,0,0,0};
    if (arow < NN){
      const float4* p = (const float4*)(X + (size_t)arow*HH + kt*32 + kgrp*8);
      float4 v0 = p[0], v1 = p[1];
      af[0]=f2b(v0.x); af[1]=f2b(v0.y); af[2]=f2b(v0.z); af[3]=f2b(v0.w);
      af[4]=f2b(v1.x); af[5]=f2b(v1.y); af[6]=f2b(v1.z); af[7]=f2b(v1.w);
    }
    #pragma unroll
    for (int nf=0;nf<32;nf++){
      bf16x8 b = *(const bf16x8*)(pkWin + ((size_t)((kt<<5)+nf)*64 + lane)*8);
      acc[nf] = MFMA(af, b, acc[nf]);
    }
  }
  #pragma unroll
  for (int nf=0;nf<32;nf++){
    #pragma unroll
    for (int r=0;r<4;r++){
      int rl = w*16 + kgrp*4 + r, col = nf*16 + ccol;
      sT[rl*512 + (col ^ ((rl&7)<<3))] = f2b(gelu_fast(acc[nf][r] + bin[col]));
    }
  }
  f32x4 a2[8];
  #pragma unroll
  for (int nf=0;nf<8;nf++) a2[nf] = (f32x4){0,0,0,0};
  const int rl_a = w*16 + (lane & 15);
  #pragma unroll
  for (int kt=0;kt<16;kt++){
    int base = kt*32 + kgrp*8;
    bf16x8 af = *(const bf16x8*)(sT + rl_a*512 + (base ^ ((rl_a&7)<<3)));
    #pragma unroll
    for (int nf=0;nf<8;nf++){
      bf16x8 b = *(const bf16x8*)(pkWout + (((kt<<3)+nf)*64 + lane)*8);
      a2[nf] = MFMA(af, b, a2[nf]);
    }
  }
  float rsum[4] = {0,0,0,0}, rsq[4] = {0,0,0,0};
  #pragma unroll
  for (int nf=0;nf<8;nf++){
    #pragma unroll
    for (int r=0;r<4;r++){
      int grow = row0 + w*16 + kgrp*4 + r, col = nf*16 + ccol;
      float prev = (grow < NN) ? X[(size_t)grow*HH + col] : 0.f;
      float x = a2[nf][r] + bout[col] + prev;
      a2[nf][r] = x;
      rsum[r] += x; rsq[r] += x*x;
    }
  }
  #pragma unroll
  for (int off=1; off<16; off<<=1){
    #pragma unroll
    for (int r=0;r<4;r++){
      rsum[r] += __shfl_xor(rsum[r], off);
      rsq[r]  += __shfl_xor(rsq[r], off);
    }
  }
  #pragma unroll
  for (int r=0;r<4;r++){
    int grow = row0 + w*16 + kgrp*4 + r;
    float mean = rsum[r]*(1.f/128.f);
    float var  = rsq[r]*(1.f/128.f) - mean*mean;
    float inv  = rsqrtf(var + LN_EPS);
    float mv   = (grow < NN) ? maskV[grow] : 0.f;
    #pragma unroll
    for (int nf=0;nf<8;nf++){
      int col = nf*16 + ccol;
      if (grow < NN)
        out[(size_t)grow*HH + col] = mv * ((a2[nf][r]-mean)*inv*g2[col] + b2ln[col]);
    }
  }
}

// ---------------- host ----------------
extern "C" void kernel_launch(void* const* d_in, const int* in_sizes, int n_in,
                              void* d_out, int out_size, void* d_ws, size_t ws_size,
                              hipStream_t stream)
{
  const float* h_V   = (const float*)d_in[0];
  const float* h_E   = (const float*)d_in[1];
  const float* maskV = (const float*)d_in[2];
  const float* maskA = (const float*)d_in[3];
  const float* W1w  = (const float*)d_in[4];  const float* W1b  = (const float*)d_in[5];
  const float* W2w  = (const float*)d_in[6];  const float* W2b  = (const float*)d_in[7];
  const float* W3w  = (const float*)d_in[8];  const float* W3b  = (const float*)d_in[9];
  const float* W11w = (const float*)d_in[10]; const float* W11b = (const float*)d_in[11];
  const float* W12w = (const float*)d_in[12]; const float* W12b = (const float*)d_in[13];
  const float* W13w = (const float*)d_in[14]; const float* W13b = (const float*)d_in[15];
  const float* Winw = (const float*)d_in[16]; const float* Winb = (const float*)d_in[17];
  const float* Woutw= (const float*)d_in[18]; const float* Woutb= (const float*)d_in[19];
  const float* ln1g = (const float*)d_in[20]; const float* ln1b = (const float*)d_in[21];
  const float* ln2g = (const float*)d_in[22]; const float* ln2b = (const float*)d_in[23];
  const float* ln3g = (const float*)d_in[24]; const float* ln3b = (const float*)d_in[25];
  const int*   Eidx = (const int*)d_in[26];

  float* outV = (float*)d_out;
  float* outE = outV + (size_t)NN*HH;

  char* ws = (char*)d_ws;
  short* pk = (short*)ws;
  const short* pkW1a  = pk + 0*16384;
  const short* pkW1c  = pk + 1*16384;
  const short* pkW1bb = pk + 2*16384;
  const short* pkW2   = pk + 3*16384;
  const short* pkW3   = pk + 4*16384;
  const short* pkW11a = pk + 5*16384;
  const short* pkW11c = pk + 6*16384;
  const short* pkW11bb= pk + 7*16384;
  const short* pkW12  = pk + 8*16384;
  const short* pkW13  = pk + 9*16384;
  const short* pkWin  = pk + 163840;
  const short* pkWout = pk + 229376;

  short* U1 = (short*)(ws + 1048576);
  short* Z1 = (short*)(ws + 6291456);
  short* U2 = (short*)(ws + 11534336);
  short* Z2 = (short*)(ws + 16777216);
  float* hVmid = (float*)(ws + 22020096);
  short* hEs = (short*)(ws + 33554432);   // bf16 image of h_E, 163.84 MB

  const bool em = ws_size >= (size_t)33554432 + (size_t)NN*KK*HH*2;

  enc_pack<<<288, 256, 0, stream>>>(W1w, W2w, W3w, W11w, W12w, W13w, Winw, Woutw, pk);
  enc_proj<<<313, 256, 0, stream>>>(h_V, pkW1a, pkW1c, W1b, U1, Z1);
  if (em){
    enc_mlp3<0,1><<<NN/4, 512, 0, stream>>>(h_E, U1, Z1, Eidx, maskA, h_V,
                                            ln1g, ln1b, pkW1bb, pkW2, W2b, pkW3, W3b, hVmid, hEs);
  } else {
    enc_mlp3<0,0><<<NN/4, 512, 0, stream>>>(h_E, U1, Z1, Eidx, maskA, h_V,
                                            ln1g, ln1b, pkW1bb, pkW2, W2b, pkW3, W3b, hVmid, nullptr);
  }
  enc_ffn<<<313, 256, 0, stream>>>(hVmid, pkWin, Winb, pkWout, Woutb,
                                   ln2g, ln2b, maskV, outV);
  enc_proj<<<313, 256, 0, stream>>>(outV, pkW11a, pkW11c, W11b, U2, Z2);
  if (em){
    enc_mlp3<1,1><<<NN/4, 512, 0, stream>>>(h_E, U2, Z2, Eidx, nullptr, nullptr,
                                            ln3g, ln3b, pkW11bb, pkW12, W12b, pkW13, W13b, outE, hEs);
  } else {
    enc_mlp3<1,0><<<NN/4, 512, 0, stream>>>(h_E, U2, Z2, Eidx, nullptr, nullptr,
                                            ln3g, ln3b, pkW11bb, pkW12, W12b, pkW13, W13b, outE, nullptr);
  }
}

// Round 15
// 390.181 us; speedup vs baseline: 1.1319x; 1.0534x over previous
//
#include <hip/hip_runtime.h>
#include <hip/hip_bf16.h>
#include <cstdint>
#include <cstddef>

#define NN 20000
#define KK 32
#define HH 128
#define FFD 512
#define LN_EPS 1e-5f

typedef __attribute__((ext_vector_type(8))) short bf16x8;
typedef __attribute__((ext_vector_type(4))) float f32x4;

__device__ __forceinline__ short f2b(float f){
  __hip_bfloat16 h = __float2bfloat16(f);
  return __builtin_bit_cast(short, h);
}
__device__ __forceinline__ float b2f(short s){
  union { unsigned int u; float f; } v; v.u = ((unsigned int)(unsigned short)s) << 16; return v.f;
}
__device__ __forceinline__ unsigned int pk2(float a, float b){
  return (unsigned int)(unsigned short)f2b(a) | ((unsigned int)(unsigned short)f2b(b) << 16);
}
// tanh-form GELU via hw exp2 + rcp
__device__ __forceinline__ float gelu_fast(float x){
  float u = x * __builtin_fmaf(0.10294278f, x*x, 2.3022082f);
  float e = __builtin_amdgcn_exp2f(u);
  float r = __builtin_amdgcn_rcpf(1.0f + e);
  return __builtin_fmaf(-x, r, x);
}
__device__ __forceinline__ f32x4 MFMA(bf16x8 a, bf16x8 b, f32x4 c){
  return __builtin_amdgcn_mfma_f32_16x16x32_bf16(a, b, c, 0, 0, 0);
}
// async global->LDS, 16B per lane; dest = wave-uniform base + lane*16
__device__ __forceinline__ void gload_lds16(const short* g, short* l){
  __builtin_amdgcn_global_load_lds(
      (const __attribute__((address_space(1))) void*)g,
      (__attribute__((address_space(3))) void*)l,
      16, 0, 0);
}

// ---------------- weight packing ----------------
__global__ __launch_bounds__(256) void enc_pack(
    const float* __restrict__ W1, const float* __restrict__ W2, const float* __restrict__ W3,
    const float* __restrict__ W11, const float* __restrict__ W12, const float* __restrict__ W13,
    const float* __restrict__ Win, const float* __restrict__ Wout,
    short* __restrict__ pk)
{
  const int stride = gridDim.x * blockDim.x;
  for (int idx = blockIdx.x*blockDim.x + threadIdx.x; idx < 294912; idx += stride){
    const float* src = W2; int srow = 0, k, n, NT, NCOLS, base;
    if (idx < 163840){
      int slot = idx >> 14, e = idx & 16383;
      k = e >> 7; n = e & 127; NT = 8; NCOLS = 128; base = slot << 14;
      switch (slot){
        case 0: src = W1;  srow = 0;   break;
        case 1: src = W1;  srow = 256; break;
        case 2: src = W1;  srow = 128; break;
        case 3: src = W2;  srow = 0;   break;
        case 4: src = W3;  srow = 0;   break;
        case 5: src = W11; srow = 0;   break;
        case 6: src = W11; srow = 256; break;
        case 7: src = W11; srow = 128; break;
        case 8: src = W12; srow = 0;   break;
        default: src = W13; srow = 0;  break;
      }
    } else if (idx < 229376){
      int e = idx - 163840; k = e >> 9; n = e & 511; NT = 32; NCOLS = 512; src = Win; base = 163840;
    } else {
      int e = idx - 229376; k = e >> 7; n = e & 127; NT = 8; NCOLS = 128; src = Wout; base = 229376;
    }
    float v = src[(srow + k)*NCOLS + n];
    int out = base + (((k>>5)*NT + (n>>4))*64 + ((k>>3)&3)*16 + (n&15))*8 + (k&7);
    pk[out] = f2b(v);
  }
}

// ---------------- node projections: U = X@Wa + b, Z = X@Wc ----------------
__global__ __launch_bounds__(256, 2) void enc_proj(
    const float* __restrict__ X, const short* __restrict__ pkU, const short* __restrict__ pkZ,
    const float* __restrict__ biasU, short* __restrict__ U, short* __restrict__ Z)
{
  const int lane = threadIdx.x & 63, w = threadIdx.x >> 6;
  const int kgrp = lane >> 4, ccol = lane & 15;
  const int row0 = blockIdx.x*64 + w*16;
  const int arow = row0 + (lane & 15);
  f32x4 accU[8], accZ[8];
  #pragma unroll
  for (int nf=0;nf<8;nf++){ accU[nf] = (f32x4){0,0,0,0}; accZ[nf] = (f32x4){0,0,0,0}; }
  #pragma unroll
  for (int kt=0;kt<4;kt++){
    bf16x8 af = {0,0,0,0,0,0,0,0};
    if (arow < NN){
      const float4* p = (const float4*)(X + (size_t)arow*HH + kt*32 + kgrp*8);
      float4 v0 = p[0], v1 = p[1];
      af[0]=f2b(v0.x); af[1]=f2b(v0.y); af[2]=f2b(v0.z); af[3]=f2b(v0.w);
      af[4]=f2b(v1.x); af[5]=f2b(v1.y); af[6]=f2b(v1.z); af[7]=f2b(v1.w);
    }
    #pragma unroll
    for (int nf=0;nf<8;nf++){
      bf16x8 bu = *(const bf16x8*)(pkU + (((kt<<3)+nf)*64 + lane)*8);
      accU[nf] = MFMA(af, bu, accU[nf]);
      bf16x8 bz = *(const bf16x8*)(pkZ + (((kt<<3)+nf)*64 + lane)*8);
      accZ[nf] = MFMA(af, bz, accZ[nf]);
    }
  }
  #pragma unroll
  for (int nf=0;nf<8;nf++){
    #pragma unroll
    for (int r=0;r<4;r++){
      int grow = row0 + kgrp*4 + r;
      if (grow < NN){
        int col = nf*16 + ccol;
        U[(size_t)grow*HH + col] = f2b(accU[nf][r] + biasU[col]);
        Z[(size_t)grow*HH + col] = f2b(accZ[nf][r]);
      }
    }
  }
}

// ---------------- fused 3-layer edge MLP (8 waves, 4 nodes/block) ----------------
// R14 chassis + register harvest: Z prefetched into 16 regs BEFORE the first
// barrier (layer-1 MFMA hides the gather latency; spill-safe: ~110 regs < 128
// cap), biases b2/b3 + PASS0 mask in registers (sB23 eliminated -> no scalar
// ds_reads in epilogues). Async W staging via global_load_lds (R14). U folded
// into layer-1 acc init. hEs bf16 image (R11).
#define LSTR 136
template<int PASS, int EM>
__global__ __launch_bounds__(512, 4) void enc_mlp3(
    const float* __restrict__ hE,
    const short* __restrict__ Ub, const short* __restrict__ Zb,
    const int*  __restrict__ Eidx,
    const float* __restrict__ maskAtt,
    const float* __restrict__ hV,
    const float* __restrict__ lnG, const float* __restrict__ lnB,
    const short* __restrict__ pkL1,
    const short* __restrict__ pkL2, const float* __restrict__ bias2,
    const short* __restrict__ pkL3, const float* __restrict__ bias3,
    float* __restrict__ outP,
    short* __restrict__ hEs)
{
  __shared__ __align__(16) short sBuf[128*LSTR];  // 34816 B activations
  __shared__ __align__(16) short sW[16384];       // 32768 B current-layer weights
  __shared__ float sPart[8][128];

  const int i0 = blockIdx.x*4;
  const int t = threadIdx.x;
  const int lane = t & 63, w = t >> 6;          // w in 0..7
  const int kgrp = lane >> 4, ccol = lane & 15;
  const int node = i0 + (w >> 1);
  const int rw = w*16;
  const size_t ebase = (size_t)i0*KK;           // first edge row of block

  // ---- stage W1 into LDS: async, 4 x 1KB per wave ----
  #pragma unroll
  for (int i=0;i<4;i++)
    gload_lds16(pkL1 + (w*4 + i)*512 + lane*8, sW + (w*4 + i)*512);

  // ---- early register loads: U, biases, mask, Z ----
  float ureg[8], b2reg[8], b3reg[8];
  #pragma unroll
  for (int nf=0; nf<8; nf++){
    int col = nf*16 + ccol;
    ureg[nf]  = b2f(Ub[(size_t)node*HH + col]);
    b2reg[nf] = bias2[col];
    b3reg[nf] = bias3[col];
  }
  float m[4];
  if (PASS == 0){
    const float4 mv = *(const float4*)(maskAtt + ebase + rw + kgrp*4);
    m[0]=mv.x; m[1]=mv.y; m[2]=mv.z; m[3]=mv.w;
  }
  // Z prefetch (16 regs, consumed after layer 1 -> full MFMA phase hides latency)
  const int zrow = rw + (lane >> 2);
  const int seg0 = lane & 3;
  const int jj = Eidx[i0*KK + zrow];
  const int4* zsrc = (const int4*)(Zb + (size_t)jj*HH);
  int4 z0g = zsrc[seg0];
  int4 z1g = zsrc[seg0 + 4];
  int4 z2g = zsrc[seg0 + 8];
  int4 z3g = zsrc[seg0 + 12];

  // ---- stage h_E rows rw..rw+15 (wave-local) ----
  if constexpr (EM == 1 && PASS == 1){
    // bf16 source: pure int4 copy
    const short* srcS = hEs + (ebase + rw)*HH;
    #pragma unroll
    for (int it=0; it<4; it++){
      int r16 = it*4 + (lane>>4);
      int c16 = lane & 15;
      int4 v = *(const int4*)(srcS + (size_t)r16*HH + c16*8);
      *(int4*)(sBuf + (rw + r16)*LSTR + c16*8) = v;
    }
  } else {
    // fp32 source -> bf16 (PASS0 always; PASS1 when EM=0)
    const float4* src = (const float4*)(hE + (ebase + rw)*HH);
    #pragma unroll
    for (int it=0; it<8; it++){
      int r = it*2 + (lane>>5);
      int c4 = lane & 31;
      float4 v = src[r*32 + c4];
      unsigned long long p = (unsigned long long)pk2(v.x, v.y)
                           | ((unsigned long long)pk2(v.z, v.w) << 32);
      *(unsigned long long*)(sBuf + (rw + r)*LSTR + c4*4) = p;
      if constexpr (EM == 1 && PASS == 0)
        __builtin_nontemporal_store(p,
            (unsigned long long*)(hEs + (ebase + rw + r)*HH + c4*4));
    }
  }
  __syncthreads();   // W1 (vmcnt-drained) visible

  const short* sRow = sBuf + (rw + ccol)*LSTR;
  f32x4 acc[8];

  // ---- layer 1 (acc init = U) ----
  #pragma unroll
  for (int nf=0;nf<8;nf++) acc[nf] = (f32x4){ureg[nf],ureg[nf],ureg[nf],ureg[nf]};
  #pragma unroll
  for (int kt=0;kt<4;kt++){
    bf16x8 af = *(const bf16x8*)(sRow + kt*32 + kgrp*8);
    #pragma unroll
    for (int nf=0;nf<8;nf++){
      bf16x8 b = *(const bf16x8*)(sW + (((kt<<3)+nf)*64 + lane)*8);
      acc[nf] = MFMA(af, b, acc[nf]);
    }
  }
  // Z write from prefetched regs (hE fragments consumed; rows wave-private)
  *(int4*)(sBuf + zrow*LSTR + (seg0     )*8) = z0g;
  *(int4*)(sBuf + zrow*LSTR + (seg0 + 4 )*8) = z1g;
  *(int4*)(sBuf + zrow*LSTR + (seg0 + 8 )*8) = z2g;
  *(int4*)(sBuf + zrow*LSTR + (seg0 + 12)*8) = z3g;
  __syncthreads();   // all waves done reading W1
  // stage W2 async (flies during epilogue-1)
  #pragma unroll
  for (int i=0;i<4;i++)
    gload_lds16(pkL2 + (w*4 + i)*512 + lane*8, sW + (w*4 + i)*512);
  // epilogue 1: +Z, gelu -> msg1
  #pragma unroll
  for (int nf=0;nf<8;nf++){
    #pragma unroll
    for (int r=0;r<4;r++){
      short* p = sBuf + (rw + kgrp*4 + r)*LSTR + nf*16 + ccol;
      float v = acc[nf][r] + b2f(*p);
      *p = f2b(gelu_fast(v));
    }
  }
  __syncthreads();   // W2 visible

  // ---- layer 2 ----
  #pragma unroll
  for (int nf=0;nf<8;nf++) acc[nf] = (f32x4){0,0,0,0};
  #pragma unroll
  for (int kt=0;kt<4;kt++){
    bf16x8 af = *(const bf16x8*)(sRow + kt*32 + kgrp*8);
    #pragma unroll
    for (int nf=0;nf<8;nf++){
      bf16x8 b = *(const bf16x8*)(sW + (((kt<<3)+nf)*64 + lane)*8);
      acc[nf] = MFMA(af, b, acc[nf]);
    }
  }
  __syncthreads();   // all waves done reading W2
  // stage W3 async (flies during epilogue-2)
  #pragma unroll
  for (int i=0;i<4;i++)
    gload_lds16(pkL3 + (w*4 + i)*512 + lane*8, sW + (w*4 + i)*512);
  #pragma unroll
  for (int nf=0;nf<8;nf++){
    #pragma unroll
    for (int r=0;r<4;r++){
      short* p = sBuf + (rw + kgrp*4 + r)*LSTR + nf*16 + ccol;
      *p = f2b(gelu_fast(acc[nf][r] + b2reg[nf]));
    }
  }
  __syncthreads();   // W3 visible

  // ---- layer 3 ----
  #pragma unroll
  for (int nf=0;nf<8;nf++) acc[nf] = (f32x4){0,0,0,0};
  #pragma unroll
  for (int kt=0;kt<4;kt++){
    bf16x8 af = *(const bf16x8*)(sRow + kt*32 + kgrp*8);
    #pragma unroll
    for (int nf=0;nf<8;nf++){
      bf16x8 b = *(const bf16x8*)(sW + (((kt<<3)+nf)*64 + lane)*8);
      acc[nf] = MFMA(af, b, acc[nf]);
    }
  }

  if (PASS == 0){
    #pragma unroll
    for (int nf=0;nf<8;nf++){
      float s = 0.f;
      #pragma unroll
      for (int r=0;r<4;r++) s = __builtin_fmaf(acc[nf][r] + b3reg[nf], m[r], s);
      s += __shfl_xor(s, 16);
      s += __shfl_xor(s, 32);
      if (kgrp == 0) sPart[w][nf*16 + ccol] = s;
    }
    __syncthreads();
    if ((w & 1) == 0){
      float c0 = sPart[w][lane]    + sPart[w+1][lane];
      float c1 = sPart[w][64+lane] + sPart[w+1][64+lane];
      float x0 = hV[(size_t)node*HH + lane]      + c0*(1.0f/30.0f);
      float x1 = hV[(size_t)node*HH + 64 + lane] + c1*(1.0f/30.0f);
      float sm = x0 + x1, sq = x0*x0 + x1*x1;
      #pragma unroll
      for (int off=1; off<64; off<<=1){
        sm += __shfl_xor(sm, off);
        sq += __shfl_xor(sq, off);
      }
      float mean = sm*(1.f/128.f);
      float var  = sq*(1.f/128.f) - mean*mean;
      float inv  = rsqrtf(var + LN_EPS);
      outP[(size_t)node*HH + lane]      = (x0-mean)*inv*lnG[lane]    + lnB[lane];
      outP[(size_t)node*HH + 64 + lane] = (x1-mean)*inv*lnG[64+lane] + lnB[64+lane];
    }
  } else {
    // +b3, +h_E residual, LN3 in-register per row
    float rs[4] = {0,0,0,0}, rq[4] = {0,0,0,0};
    #pragma unroll
    for (int nf=0;nf<8;nf++){
      #pragma unroll
      for (int r=0;r<4;r++){
        int row = rw + kgrp*4 + r, col = nf*16 + ccol;
        float hres;
        if constexpr (EM == 1) hres = b2f(hEs[(ebase + row)*HH + col]);
        else                   hres = hE[(ebase + row)*HH + col];
        float x = acc[nf][r] + b3reg[nf] + hres;
        acc[nf][r] = x;
        rs[r] += x; rq[r] += x*x;
      }
    }
    #pragma unroll
    for (int off=1; off<16; off<<=1){
      #pragma unroll
      for (int r=0;r<4;r++){
        rs[r] += __shfl_xor(rs[r], off);
        rq[r] += __shfl_xor(rq[r], off);
      }
    }
    #pragma unroll
    for (int r=0;r<4;r++){
      float mean = rs[r]*(1.f/128.f);
      float var  = rq[r]*(1.f/128.f) - mean*mean;
      float inv  = rsqrtf(var + LN_EPS);
      #pragma unroll
      for (int nf=0;nf<8;nf++){
        int row = rw + kgrp*4 + r, col = nf*16 + ccol;
        __builtin_nontemporal_store((acc[nf][r]-mean)*inv*lnG[col] + lnB[col],
                                    &outP[(ebase + row)*HH + col]);
      }
    }
  }
}

// ---------------- fused FFN 128->512->128 + LN2 + mask_V ----------------
__global__ __launch_bounds__(256, 2) void enc_ffn(
    const float* __restrict__ X,
    const short* __restrict__ pkWin, const float* __restrict__ bin,
    const short* __restrict__ pkWout, const float* __restrict__ bout,
    const float* __restrict__ g2, const float* __restrict__ b2ln,
    const float* __restrict__ maskV,
    float* __restrict__ out)
{
  __shared__ short sT[64*512];
  const int t = threadIdx.x, lane = t & 63, w = t >> 6;
  const int kgrp = lane >> 4, ccol = lane & 15;
  const int row0 = blockIdx.x*64;
  const int arow = row0 + w*16 + (lane & 15);
  f32x4 acc[32];
  #pragma unroll
  for (int nf=0;nf<32;nf++) acc[nf] = (f32x4){0,0,0,0};
  #pragma unroll
  for (int kt=0;kt<4;kt++){
    bf16x8 af = {0,0,0,0,0,0,0,0};
    if (arow < NN){
      const float4* p = (const float4*)(X + (size_t)arow*HH + kt*32 + kgrp*8);
      float4 v0 = p[0], v1 = p[1];
      af[0]=f2b(v0.x); af[1]=f2b(v0.y); af[2]=f2b(v0.z); af[3]=f2b(v0.w);
      af[4]=f2b(v1.x); af[5]=f2b(v1.y); af[6]=f2b(v1.z); af[7]=f2b(v1.w);
    }
    #pragma unroll
    for (int nf=0;nf<32;nf++){
      bf16x8 b = *(const bf16x8*)(pkWin + ((size_t)((kt<<5)+nf)*64 + lane)*8);
      acc[nf] = MFMA(af, b, acc[nf]);
    }
  }
  #pragma unroll
  for (int nf=0;nf<32;nf++){
    #pragma unroll
    for (int r=0;r<4;r++){
      int rl = w*16 + kgrp*4 + r, col = nf*16 + ccol;
      sT[rl*512 + (col ^ ((rl&7)<<3))] = f2b(gelu_fast(acc[nf][r] + bin[col]));
    }
  }
  f32x4 a2[8];
  #pragma unroll
  for (int nf=0;nf<8;nf++) a2[nf] = (f32x4){0,0,0,0};
  const int rl_a = w*16 + (lane & 15);
  #pragma unroll
  for (int kt=0;kt<16;kt++){
    int base = kt*32 + kgrp*8;
    bf16x8 af = *(const bf16x8*)(sT + rl_a*512 + (base ^ ((rl_a&7)<<3)));
    #pragma unroll
    for (int nf=0;nf<8;nf++){
      bf16x8 b = *(const bf16x8*)(pkWout + (((kt<<3)+nf)*64 + lane)*8);
      a2[nf] = MFMA(af, b, a2[nf]);
    }
  }
  float rsum[4] = {0,0,0,0}, rsq[4] = {0,0,0,0};
  #pragma unroll
  for (int nf=0;nf<8;nf++){
    #pragma unroll
    for (int r=0;r<4;r++){
      int grow = row0 + w*16 + kgrp*4 + r, col = nf*16 + ccol;
      float prev = (grow < NN) ? X[(size_t)grow*HH + col] : 0.f;
      float x = a2[nf][r] + bout[col] + prev;
      a2[nf][r] = x;
      rsum[r] += x; rsq[r] += x*x;
    }
  }
  #pragma unroll
  for (int off=1; off<16; off<<=1){
    #pragma unroll
    for (int r=0;r<4;r++){
      rsum[r] += __shfl_xor(rsum[r], off);
      rsq[r]  += __shfl_xor(rsq[r], off);
    }
  }
  #pragma unroll
  for (int r=0;r<4;r++){
    int grow = row0 + w*16 + kgrp*4 + r;
    float mean = rsum[r]*(1.f/128.f);
    float var  = rsq[r]*(1.f/128.f) - mean*mean;
    float inv  = rsqrtf(var + LN_EPS);
    float mv   = (grow < NN) ? maskV[grow] : 0.f;
    #pragma unroll
    for (int nf=0;nf<8;nf++){
      int col = nf*16 + ccol;
      if (grow < NN)
        out[(size_t)grow*HH + col] = mv * ((a2[nf][r]-mean)*inv*g2[col] + b2ln[col]);
    }
  }
}

// ---------------- host ----------------
extern "C" void kernel_launch(void* const* d_in, const int* in_sizes, int n_in,
                              void* d_out, int out_size, void* d_ws, size_t ws_size,
                              hipStream_t stream)
{
  const float* h_V   = (const float*)d_in[0];
  const float* h_E   = (const float*)d_in[1];
  const float* maskV = (const float*)d_in[2];
  const float* maskA = (const float*)d_in[3];
  const float* W1w  = (const float*)d_in[4];  const float* W1b  = (const float*)d_in[5];
  const float* W2w  = (const float*)d_in[6];  const float* W2b  = (const float*)d_in[7];
  const float* W3w  = (const float*)d_in[8];  const float* W3b  = (const float*)d_in[9];
  const float* W11w = (const float*)d_in[10]; const float* W11b = (const float*)d_in[11];
  const float* W12w = (const float*)d_in[12]; const float* W12b = (const float*)d_in[13];
  const float* W13w = (const float*)d_in[14]; const float* W13b = (const float*)d_in[15];
  const float* Winw = (const float*)d_in[16]; const float* Winb = (const float*)d_in[17];
  const float* Woutw= (const float*)d_in[18]; const float* Woutb= (const float*)d_in[19];
  const float* ln1g = (const float*)d_in[20]; const float* ln1b = (const float*)d_in[21];
  const float* ln2g = (const float*)d_in[22]; const float* ln2b = (const float*)d_in[23];
  const float* ln3g = (const float*)d_in[24]; const float* ln3b = (const float*)d_in[25];
  const int*   Eidx = (const int*)d_in[26];

  float* outV = (float*)d_out;
  float* outE = outV + (size_t)NN*HH;

  char* ws = (char*)d_ws;
  short* pk = (short*)ws;
  const short* pkW1a  = pk + 0*16384;
  const short* pkW1c  = pk + 1*16384;
  const short* pkW1bb = pk + 2*16384;
  const short* pkW2   = pk + 3*16384;
  const short* pkW3   = pk + 4*16384;
  const short* pkW11a = pk + 5*16384;
  const short* pkW11c = pk + 6*16384;
  const short* pkW11bb= pk + 7*16384;
  const short* pkW12  = pk + 8*16384;
  const short* pkW13  = pk + 9*16384;
  const short* pkWin  = pk + 163840;
  const short* pkWout = pk + 229376;

  short* U1 = (short*)(ws + 1048576);
  short* Z1 = (short*)(ws + 6291456);
  short* U2 = (short*)(ws + 11534336);
  short* Z2 = (short*)(ws + 16777216);
  float* hVmid = (float*)(ws + 22020096);
  short* hEs = (short*)(ws + 33554432);   // bf16 image of h_E, 163.84 MB

  const bool em = ws_size >= (size_t)33554432 + (size_t)NN*KK*HH*2;

  enc_pack<<<288, 256, 0, stream>>>(W1w, W2w, W3w, W11w, W12w, W13w, Winw, Woutw, pk);
  enc_proj<<<313, 256, 0, stream>>>(h_V, pkW1a, pkW1c, W1b, U1, Z1);
  if (em){
    enc_mlp3<0,1><<<NN/4, 512, 0, stream>>>(h_E, U1, Z1, Eidx, maskA, h_V,
                                            ln1g, ln1b, pkW1bb, pkW2, W2b, pkW3, W3b, hVmid, hEs);
  } else {
    enc_mlp3<0,0><<<NN/4, 512, 0, stream>>>(h_E, U1, Z1, Eidx, maskA, h_V,
                                            ln1g, ln1b, pkW1bb, pkW2, W2b, pkW3, W3b, hVmid, nullptr);
  }
  enc_ffn<<<313, 256, 0, stream>>>(hVmid, pkWin, Winb, pkWout, Woutb,
                                   ln2g, ln2b, maskV, outV);
  enc_proj<<<313, 256, 0, stream>>>(outV, pkW11a, pkW11c, W11b, U2, Z2);
  if (em){
    enc_mlp3<1,1><<<NN/4, 512, 0, stream>>>(h_E, U2, Z2, Eidx, nullptr, nullptr,
                                            ln3g, ln3b, pkW11bb, pkW12, W12b, pkW13, W13b, outE, hEs);
  } else {
    enc_mlp3<1,0><<<NN/4, 512, 0, stream>>>(h_E, U2, Z2, Eidx, nullptr, nullptr,
                                            ln3g, ln3b, pkW11bb, pkW12, W12b, pkW13, W13b, outE, nullptr);
  }
}